// Round 1
// baseline (577.113 us; speedup 1.0000x reference)
//
#include <hip/hip_runtime.h>
#include <hip/hip_bf16.h>
#include <cstdint>
#include <cstddef>

// ---------------------------------------------------------------------------
// GAT 2-layer forward. N=50000, E=800000 (+N self loops), H=8 heads.
// Layer1: Fin=128 -> 8x32 (=256), lrelu(0.2). Layer2: 256 -> 8x4 (=32).
// Strategy: build CSR-by-dst each call (histogram + scan + scatter), dense
// fp32 GEMMs on vector ALU (no fp32 MFMA on CDNA4), then one wave per dst
// node does the segment softmax + weighted aggregation.
// ---------------------------------------------------------------------------

__device__ __forceinline__ float lrelu(float a) { return a > 0.f ? a : 0.2f * a; }

// -------------------- CSR build --------------------

__global__ __launch_bounds__(256) void k_hist(const int* __restrict__ dste, int E, int n,
                                              int* __restrict__ cnt) {
  int t = blockIdx.x * 256 + threadIdx.x;
  if (t >= E + n) return;
  int d = (t < E) ? dste[t] : (t - E);   // self-loop for node t-E
  atomicAdd(&cnt[d], 1);
}

__global__ __launch_bounds__(256) void k_scan1(const int* __restrict__ cnt, int n,
                                               int* __restrict__ bsum) {
  __shared__ int sb[256];
  int i0 = blockIdx.x * 1024 + threadIdx.x * 4;
  int s = 0;
#pragma unroll
  for (int j = 0; j < 4; j++) { int i = i0 + j; if (i < n) s += cnt[i]; }
  sb[threadIdx.x] = s;
  __syncthreads();
  for (int off = 128; off > 0; off >>= 1) {
    if (threadIdx.x < off) sb[threadIdx.x] += sb[threadIdx.x + off];
    __syncthreads();
  }
  if (threadIdx.x == 0) bsum[blockIdx.x] = sb[0];
}

__global__ void k_scan2(const int* __restrict__ bsum, int nb, int* __restrict__ boff,
                        int* __restrict__ row_ptr, int n) {
  if (threadIdx.x == 0 && blockIdx.x == 0) {
    int run = 0;
    for (int j = 0; j < nb; j++) { boff[j] = run; run += bsum[j]; }
    row_ptr[n] = run;
  }
}

__global__ __launch_bounds__(256) void k_scan3(const int* __restrict__ cnt,
                                               const int* __restrict__ boff, int n,
                                               int* __restrict__ row_ptr,
                                               int* __restrict__ cursor) {
  __shared__ int sb[256];
  int i0 = blockIdx.x * 1024 + threadIdx.x * 4;
  int c[4];
  int s = 0;
#pragma unroll
  for (int j = 0; j < 4; j++) { int i = i0 + j; c[j] = (i < n) ? cnt[i] : 0; s += c[j]; }
  sb[threadIdx.x] = s;
  __syncthreads();
  for (int off = 1; off < 256; off <<= 1) {
    int add = (threadIdx.x >= off) ? sb[threadIdx.x - off] : 0;
    __syncthreads();
    sb[threadIdx.x] += add;
    __syncthreads();
  }
  int excl = sb[threadIdx.x] - s + boff[blockIdx.x];
#pragma unroll
  for (int j = 0; j < 4; j++) {
    int i = i0 + j;
    if (i < n) { row_ptr[i] = excl; cursor[i] = excl; excl += c[j]; }
  }
}

__global__ __launch_bounds__(256) void k_scatter(const int* __restrict__ srce,
                                                 const int* __restrict__ dste, int E, int n,
                                                 int* __restrict__ cursor,
                                                 int* __restrict__ srcs) {
  int t = blockIdx.x * 256 + threadIdx.x;
  if (t >= E + n) return;
  int s, d;
  if (t < E) { s = srce[t]; d = dste[t]; } else { s = d = t - E; }
  int pos = atomicAdd(&cursor[d], 1);
  srcs[pos] = s;
}

// -------------------- GEMMs (fp32 vector ALU) --------------------

// X[M,128] @ W[128,256] -> Y[M,256]. Block: 64 rows, 256 threads.
__global__ __launch_bounds__(256) void gemm1(const float* __restrict__ X,
                                             const float* __restrict__ W,
                                             float* __restrict__ Y, int M) {
  __shared__ float lx[64 * 128];  // 32 KB
  int row0 = blockIdx.x * 64;
#pragma unroll
  for (int i = 0; i < 8; i++) {
    int j = threadIdx.x + 256 * i;   // float4 index, 2048 total
    int r = j >> 5;                  // row within tile
    float4 v = make_float4(0.f, 0.f, 0.f, 0.f);
    if (row0 + r < M) v = *(const float4*)&X[(size_t)row0 * 128 + (size_t)j * 4];
    *(float4*)&lx[j * 4] = v;
  }
  __syncthreads();
  int tc = threadIdx.x & 63;   // col group: cols 4*tc..4*tc+3
  int tr = threadIdx.x >> 6;   // row group: rows tr*16..tr*16+15
  const float* lrow = &lx[tr * 16 * 128];
  float4 acc[16];
#pragma unroll
  for (int i = 0; i < 16; i++) acc[i] = make_float4(0.f, 0.f, 0.f, 0.f);
  for (int k = 0; k < 128; k++) {
    float4 w4 = *(const float4*)&W[k * 256 + tc * 4];
#pragma unroll
    for (int i = 0; i < 16; i++) {
      float xv = lrow[i * 128 + k];   // wave-uniform address -> LDS broadcast
      acc[i].x = fmaf(xv, w4.x, acc[i].x);
      acc[i].y = fmaf(xv, w4.y, acc[i].y);
      acc[i].z = fmaf(xv, w4.z, acc[i].z);
      acc[i].w = fmaf(xv, w4.w, acc[i].w);
    }
  }
#pragma unroll
  for (int i = 0; i < 16; i++) {
    int r = row0 + tr * 16 + i;
    if (r < M) *(float4*)&Y[(size_t)r * 256 + tc * 4] = acc[i];
  }
}

// X[M,256] @ W[256,32] -> Y[M,32]. Block: 64 rows, 256 threads, K-chunks of 128.
__global__ __launch_bounds__(256) void gemm2(const float* __restrict__ X,
                                             const float* __restrict__ W,
                                             float* __restrict__ Y, int M) {
  __shared__ float lx[64 * 132];  // padded stride 132 (2-way LDS conflict = free)
  int row0 = blockIdx.x * 64;
  int tc = threadIdx.x & 7;    // cols 4*tc..4*tc+3
  int tr = threadIdx.x >> 3;   // rows tr*2, tr*2+1
  float4 acc[2];
  acc[0] = make_float4(0.f, 0.f, 0.f, 0.f);
  acc[1] = make_float4(0.f, 0.f, 0.f, 0.f);
  for (int kk = 0; kk < 256; kk += 128) {
    __syncthreads();
#pragma unroll
    for (int i = 0; i < 8; i++) {
      int j = threadIdx.x + 256 * i;  // float4 index, 2048 total
      int r = j >> 5;
      int c = (j & 31) * 4;
      float4 v = make_float4(0.f, 0.f, 0.f, 0.f);
      if (row0 + r < M) v = *(const float4*)&X[(size_t)(row0 + r) * 256 + kk + c];
      *(float4*)&lx[r * 132 + c] = v;  // 132%4==0 -> 16B aligned
    }
    __syncthreads();
    for (int k = 0; k < 128; k++) {
      float4 w4 = *(const float4*)&W[(kk + k) * 32 + tc * 4];
#pragma unroll
      for (int i = 0; i < 2; i++) {
        float xv = lx[(tr * 2 + i) * 132 + k];
        acc[i].x = fmaf(xv, w4.x, acc[i].x);
        acc[i].y = fmaf(xv, w4.y, acc[i].y);
        acc[i].z = fmaf(xv, w4.z, acc[i].z);
        acc[i].w = fmaf(xv, w4.w, acc[i].w);
      }
    }
  }
#pragma unroll
  for (int i = 0; i < 2; i++) {
    int r = row0 + tr * 2 + i;
    if (r < M) *(float4*)&Y[(size_t)r * 32 + tc * 4] = acc[i];
  }
}

// -------------------- attention logits per node --------------------

// asrc[n,h] = sum_c h[n,h,c]*a_src[h,c]; adst likewise. One thread per (n,h).
template <int C>
__global__ __launch_bounds__(256) void calc_alpha(const float* __restrict__ h,
                                                  const float* __restrict__ a_src,
                                                  const float* __restrict__ a_dst,
                                                  float* __restrict__ asrc,
                                                  float* __restrict__ adst, int n) {
  int t = blockIdx.x * 256 + threadIdx.x;
  if (t >= n * 8) return;
  int node = t >> 3, hh = t & 7;
  const float* hp = h + (size_t)node * 8 * C + hh * C;
  const float* as = a_src + hh * C;
  const float* ad = a_dst + hh * C;
  float s1 = 0.f, s2 = 0.f;
#pragma unroll
  for (int c = 0; c < C; c++) {
    float v = hp[c];
    s1 = fmaf(v, as[c], s1);
    s2 = fmaf(v, ad[c], s2);
  }
  asrc[t] = s1;
  adst[t] = s2;
}

// -------------------- segment softmax + aggregation --------------------

// One wave (64 lanes) per dst node. C=32 (F=256): lane owns float4 at f=lane*4,
// head = lane>>3. C=4 (F=32): lanes 0..7 own float4, head = lane.
template <int C, bool RELU>
__global__ __launch_bounds__(256) void gat_agg(const float* __restrict__ h,
                                               const float* __restrict__ asrc,
                                               const float* __restrict__ adst,
                                               const int* __restrict__ row_ptr,
                                               const int* __restrict__ srcs,
                                               const float* __restrict__ bias,
                                               float* __restrict__ out, int n) {
  constexpr int F = 8 * C;
  int wave = threadIdx.x >> 6;
  int lane = threadIdx.x & 63;
  int d = blockIdx.x * 4 + wave;
  if (d >= n) return;
  int begin = row_ptr[d];
  int end = row_ptr[d + 1];
  int head8 = lane & 7;
  float ad = adst[d * 8 + head8];

  // Pass 1: per-head max over edges. 8 edges x 8 heads in parallel.
  float m = -3.4e38f;
  for (int base = begin; base < end; base += 8) {
    int e = base + (lane >> 3);
    if (e < end) {
      int s = srcs[e];
      float a = lrelu(asrc[s * 8 + head8] + ad);
      m = fmaxf(m, a);
    }
  }
  m = fmaxf(m, __shfl_xor(m, 8));
  m = fmaxf(m, __shfl_xor(m, 16));
  m = fmaxf(m, __shfl_xor(m, 32));
  // lane l now holds max for head l&7 (lanes 0..7 hold their own head's max)

  const int myhead = (C == 32) ? (lane >> 3) : lane;
  const bool active = (C == 32) || (lane < 8);
  float denom = 0.f;
  float4 acc = make_float4(0.f, 0.f, 0.f, 0.f);
  for (int e = begin; e < end; ++e) {
    int s = srcs[e];  // wave-uniform
    float w = 0.f;
    if (lane < 8) {
      float a = lrelu(asrc[s * 8 + lane] + ad);  // lane<8: head8==lane
      w = __expf(a - m);
      denom += w;
    }
    float wh = __shfl(w, myhead);
    if (active) {
      const float4 hv = *(const float4*)&h[(size_t)s * F + lane * 4];
      acc.x = fmaf(wh, hv.x, acc.x);
      acc.y = fmaf(wh, hv.y, acc.y);
      acc.z = fmaf(wh, hv.z, acc.z);
      acc.w = fmaf(wh, hv.w, acc.w);
    }
  }
  float dn = __shfl(denom, myhead) + 1e-16f;
  if (active) {
    float inv = 1.f / dn;
    int f = lane * 4;
    float4 bv = *(const float4*)&bias[f];
    float4 r;
    r.x = acc.x * inv + bv.x;
    r.y = acc.y * inv + bv.y;
    r.z = acc.z * inv + bv.z;
    r.w = acc.w * inv + bv.w;
    if (RELU) {
      r.x = lrelu(r.x); r.y = lrelu(r.y); r.z = lrelu(r.z); r.w = lrelu(r.w);
    }
    *(float4*)&out[(size_t)d * F + f] = r;
  }
}

// -------------------- launcher --------------------

extern "C" void kernel_launch(void* const* d_in, const int* in_sizes, int n_in,
                              void* d_out, int out_size, void* d_ws, size_t ws_size,
                              hipStream_t stream) {
  const float* x   = (const float*)d_in[0];
  const int*   ei  = (const int*)d_in[1];
  const float* W1  = (const float*)d_in[2];
  const float* as1 = (const float*)d_in[3];
  const float* ad1 = (const float*)d_in[4];
  const float* b1  = (const float*)d_in[5];
  const float* W2  = (const float*)d_in[6];
  const float* as2 = (const float*)d_in[7];
  const float* ad2 = (const float*)d_in[8];
  const float* b2  = (const float*)d_in[9];
  float* out = (float*)d_out;

  const int E = in_sizes[1] / 2;
  const int n = in_sizes[0] / 128;
  const int* srce = ei;
  const int* dste = ei + E;

  char* ws = (char*)d_ws;
  size_t off = 0;
  auto alloc = [&](size_t bytes) -> void* {
    void* p = ws + off;
    off = (off + bytes + 255) & ~(size_t)255;
    return p;
  };
  int* cnt      = (int*)alloc((size_t)n * 4);
  int* row_ptr  = (int*)alloc((size_t)(n + 1) * 4);
  int* cursor   = (int*)alloc((size_t)n * 4);
  int* bsum     = (int*)alloc(256 * 4);
  int* boff     = (int*)alloc(256 * 4);
  int* srcs     = (int*)alloc((size_t)(E + n) * 4);
  float* h1     = (float*)alloc((size_t)n * 256 * 4);
  float* a_s1   = (float*)alloc((size_t)n * 8 * 4);
  float* a_d1   = (float*)alloc((size_t)n * 8 * 4);
  float* x2     = (float*)alloc((size_t)n * 256 * 4);
  float* h2     = (float*)alloc((size_t)n * 32 * 4);
  float* a_s2   = (float*)alloc((size_t)n * 8 * 4);
  float* a_d2   = (float*)alloc((size_t)n * 8 * 4);

  const int tot = E + n;
  hipMemsetAsync(cnt, 0, (size_t)n * 4, stream);
  k_hist<<<(tot + 255) / 256, 256, 0, stream>>>(dste, E, n, cnt);
  const int nb = (n + 1023) / 1024;
  k_scan1<<<nb, 256, 0, stream>>>(cnt, n, bsum);
  k_scan2<<<1, 64, 0, stream>>>(bsum, nb, boff, row_ptr, n);
  k_scan3<<<nb, 256, 0, stream>>>(cnt, boff, n, row_ptr, cursor);
  k_scatter<<<(tot + 255) / 256, 256, 0, stream>>>(srce, dste, E, n, cursor, srcs);

  gemm1<<<(n + 63) / 64, 256, 0, stream>>>(x, W1, h1, n);
  calc_alpha<32><<<(n * 8 + 255) / 256, 256, 0, stream>>>(h1, as1, ad1, a_s1, a_d1, n);
  gat_agg<32, true><<<(n + 3) / 4, 256, 0, stream>>>(h1, a_s1, a_d1, row_ptr, srcs, b1, x2, n);

  gemm2<<<(n + 63) / 64, 256, 0, stream>>>(x2, W2, h2, n);
  calc_alpha<4><<<(n * 8 + 255) / 256, 256, 0, stream>>>(h2, as2, ad2, a_s2, a_d2, n);
  gat_agg<4, false><<<(n + 3) / 4, 256, 0, stream>>>(h2, a_s2, a_d2, row_ptr, srcs, b2, out, n);
}

// Round 2
// 459.012 us; speedup vs baseline: 1.2573x; 1.2573x over previous
//
#include <hip/hip_runtime.h>
#include <hip/hip_bf16.h>
#include <cstdint>
#include <cstddef>

// ---------------------------------------------------------------------------
// GAT 2-layer forward. N=50000, E=800000 (+N self loops), H=8 heads.
// Layer1: Fin=128 -> 8x32 (=256), lrelu(0.2). Layer2: 256 -> 8x4 (=32).
// R1: (a) layer-1 aggregation unrolled x4 over edges for memory-level
// parallelism; (b) layer-2 aggregation made edge-parallel (8 edges/wave);
// (c) gemm1 inner loop k-chunked by 4 with ds_read_b128 broadcasts.
// ---------------------------------------------------------------------------

__device__ __forceinline__ float lrelu(float a) { return a > 0.f ? a : 0.2f * a; }

// -------------------- CSR build --------------------

__global__ __launch_bounds__(256) void k_hist(const int* __restrict__ dste, int E, int n,
                                              int* __restrict__ cnt) {
  int t = blockIdx.x * 256 + threadIdx.x;
  if (t >= E + n) return;
  int d = (t < E) ? dste[t] : (t - E);   // self-loop for node t-E
  atomicAdd(&cnt[d], 1);
}

__global__ __launch_bounds__(256) void k_scan1(const int* __restrict__ cnt, int n,
                                               int* __restrict__ bsum) {
  __shared__ int sb[256];
  int i0 = blockIdx.x * 1024 + threadIdx.x * 4;
  int s = 0;
#pragma unroll
  for (int j = 0; j < 4; j++) { int i = i0 + j; if (i < n) s += cnt[i]; }
  sb[threadIdx.x] = s;
  __syncthreads();
  for (int off = 128; off > 0; off >>= 1) {
    if (threadIdx.x < off) sb[threadIdx.x] += sb[threadIdx.x + off];
    __syncthreads();
  }
  if (threadIdx.x == 0) bsum[blockIdx.x] = sb[0];
}

__global__ void k_scan2(const int* __restrict__ bsum, int nb, int* __restrict__ boff,
                        int* __restrict__ row_ptr, int n) {
  if (threadIdx.x == 0 && blockIdx.x == 0) {
    int run = 0;
    for (int j = 0; j < nb; j++) { boff[j] = run; run += bsum[j]; }
    row_ptr[n] = run;
  }
}

__global__ __launch_bounds__(256) void k_scan3(const int* __restrict__ cnt,
                                               const int* __restrict__ boff, int n,
                                               int* __restrict__ row_ptr,
                                               int* __restrict__ cursor) {
  __shared__ int sb[256];
  int i0 = blockIdx.x * 1024 + threadIdx.x * 4;
  int c[4];
  int s = 0;
#pragma unroll
  for (int j = 0; j < 4; j++) { int i = i0 + j; c[j] = (i < n) ? cnt[i] : 0; s += c[j]; }
  sb[threadIdx.x] = s;
  __syncthreads();
  for (int off = 1; off < 256; off <<= 1) {
    int add = (threadIdx.x >= off) ? sb[threadIdx.x - off] : 0;
    __syncthreads();
    sb[threadIdx.x] += add;
    __syncthreads();
  }
  int excl = sb[threadIdx.x] - s + boff[blockIdx.x];
#pragma unroll
  for (int j = 0; j < 4; j++) {
    int i = i0 + j;
    if (i < n) { row_ptr[i] = excl; cursor[i] = excl; excl += c[j]; }
  }
}

__global__ __launch_bounds__(256) void k_scatter(const int* __restrict__ srce,
                                                 const int* __restrict__ dste, int E, int n,
                                                 int* __restrict__ cursor,
                                                 int* __restrict__ srcs) {
  int t = blockIdx.x * 256 + threadIdx.x;
  if (t >= E + n) return;
  int s, d;
  if (t < E) { s = srce[t]; d = dste[t]; } else { s = d = t - E; }
  int pos = atomicAdd(&cursor[d], 1);
  srcs[pos] = s;
}

// -------------------- GEMMs (fp32 vector ALU) --------------------

// X[M,128] @ W[128,256] -> Y[M,256]. Block: 64 rows, 256 threads.
// Inner loop chunked by 4 k: one ds_read_b128 broadcast per 16 FMAs.
__global__ __launch_bounds__(256) void gemm1(const float* __restrict__ X,
                                             const float* __restrict__ W,
                                             float* __restrict__ Y, int M) {
  __shared__ float lx[64 * 128];  // 32 KB
  int row0 = blockIdx.x * 64;
#pragma unroll
  for (int i = 0; i < 8; i++) {
    int j = threadIdx.x + 256 * i;   // float4 index, 2048 total
    int r = j >> 5;                  // row within tile
    float4 v = make_float4(0.f, 0.f, 0.f, 0.f);
    if (row0 + r < M) v = *(const float4*)&X[(size_t)row0 * 128 + (size_t)j * 4];
    *(float4*)&lx[j * 4] = v;
  }
  __syncthreads();
  int tc = threadIdx.x & 63;   // col group: cols 4*tc..4*tc+3
  int tr = threadIdx.x >> 6;   // row group: rows tr*16..tr*16+15
  const float* lrow = &lx[tr * 16 * 128];
  float4 acc[16];
#pragma unroll
  for (int i = 0; i < 16; i++) acc[i] = make_float4(0.f, 0.f, 0.f, 0.f);
  for (int k4 = 0; k4 < 128; k4 += 4) {
    float4 w0 = *(const float4*)&W[(k4 + 0) * 256 + tc * 4];
    float4 w1 = *(const float4*)&W[(k4 + 1) * 256 + tc * 4];
    float4 w2 = *(const float4*)&W[(k4 + 2) * 256 + tc * 4];
    float4 w3 = *(const float4*)&W[(k4 + 3) * 256 + tc * 4];
#pragma unroll
    for (int i = 0; i < 16; i++) {
      float4 xv = *(const float4*)&lrow[i * 128 + k4];  // wave-uniform b128 broadcast
      acc[i].x = fmaf(xv.x, w0.x, acc[i].x);
      acc[i].y = fmaf(xv.x, w0.y, acc[i].y);
      acc[i].z = fmaf(xv.x, w0.z, acc[i].z);
      acc[i].w = fmaf(xv.x, w0.w, acc[i].w);
      acc[i].x = fmaf(xv.y, w1.x, acc[i].x);
      acc[i].y = fmaf(xv.y, w1.y, acc[i].y);
      acc[i].z = fmaf(xv.y, w1.z, acc[i].z);
      acc[i].w = fmaf(xv.y, w1.w, acc[i].w);
      acc[i].x = fmaf(xv.z, w2.x, acc[i].x);
      acc[i].y = fmaf(xv.z, w2.y, acc[i].y);
      acc[i].z = fmaf(xv.z, w2.z, acc[i].z);
      acc[i].w = fmaf(xv.z, w2.w, acc[i].w);
      acc[i].x = fmaf(xv.w, w3.x, acc[i].x);
      acc[i].y = fmaf(xv.w, w3.y, acc[i].y);
      acc[i].z = fmaf(xv.w, w3.z, acc[i].z);
      acc[i].w = fmaf(xv.w, w3.w, acc[i].w);
    }
  }
#pragma unroll
  for (int i = 0; i < 16; i++) {
    int r = row0 + tr * 16 + i;
    if (r < M) *(float4*)&Y[(size_t)r * 256 + tc * 4] = acc[i];
  }
}

// X[M,256] @ W[256,32] -> Y[M,32]. Block: 64 rows, 256 threads, K-chunks of 128.
__global__ __launch_bounds__(256) void gemm2(const float* __restrict__ X,
                                             const float* __restrict__ W,
                                             float* __restrict__ Y, int M) {
  __shared__ float lx[64 * 132];  // padded stride 132 (2-way LDS conflict = free)
  int row0 = blockIdx.x * 64;
  int tc = threadIdx.x & 7;    // cols 4*tc..4*tc+3
  int tr = threadIdx.x >> 3;   // rows tr*2, tr*2+1
  float4 acc[2];
  acc[0] = make_float4(0.f, 0.f, 0.f, 0.f);
  acc[1] = make_float4(0.f, 0.f, 0.f, 0.f);
  for (int kk = 0; kk < 256; kk += 128) {
    __syncthreads();
#pragma unroll
    for (int i = 0; i < 8; i++) {
      int j = threadIdx.x + 256 * i;  // float4 index, 2048 total
      int r = j >> 5;
      int c = (j & 31) * 4;
      float4 v = make_float4(0.f, 0.f, 0.f, 0.f);
      if (row0 + r < M) v = *(const float4*)&X[(size_t)(row0 + r) * 256 + kk + c];
      *(float4*)&lx[r * 132 + c] = v;  // 132%4==0 -> 16B aligned
    }
    __syncthreads();
    for (int k = 0; k < 128; k++) {
      float4 w4 = *(const float4*)&W[(kk + k) * 32 + tc * 4];
#pragma unroll
      for (int i = 0; i < 2; i++) {
        float xv = lx[(tr * 2 + i) * 132 + k];
        acc[i].x = fmaf(xv, w4.x, acc[i].x);
        acc[i].y = fmaf(xv, w4.y, acc[i].y);
        acc[i].z = fmaf(xv, w4.z, acc[i].z);
        acc[i].w = fmaf(xv, w4.w, acc[i].w);
      }
    }
  }
#pragma unroll
  for (int i = 0; i < 2; i++) {
    int r = row0 + tr * 2 + i;
    if (r < M) *(float4*)&Y[(size_t)r * 32 + tc * 4] = acc[i];
  }
}

// -------------------- attention logits per node --------------------

template <int C>
__global__ __launch_bounds__(256) void calc_alpha(const float* __restrict__ h,
                                                  const float* __restrict__ a_src,
                                                  const float* __restrict__ a_dst,
                                                  float* __restrict__ asrc,
                                                  float* __restrict__ adst, int n) {
  int t = blockIdx.x * 256 + threadIdx.x;
  if (t >= n * 8) return;
  int node = t >> 3, hh = t & 7;
  const float* hp = h + (size_t)node * 8 * C + hh * C;
  const float* as = a_src + hh * C;
  const float* ad = a_dst + hh * C;
  float s1 = 0.f, s2 = 0.f;
#pragma unroll
  for (int c = 0; c < C; c++) {
    float v = hp[c];
    s1 = fmaf(v, as[c], s1);
    s2 = fmaf(v, ad[c], s2);
  }
  asrc[t] = s1;
  adst[t] = s2;
}

// -------------------- segment softmax + aggregation --------------------

// Layer 1: C=32, F=256. One wave per dst node; lane owns float4 at f=lane*4,
// head = lane>>3. Weighted-accumulate loop unrolled x4 for MLP.
__global__ __launch_bounds__(256) void gat_agg_l1(const float* __restrict__ h,
                                                  const float* __restrict__ asrc,
                                                  const float* __restrict__ adst,
                                                  const int* __restrict__ row_ptr,
                                                  const int* __restrict__ srcs,
                                                  const float* __restrict__ bias,
                                                  float* __restrict__ out, int n) {
  int wave = threadIdx.x >> 6;
  int lane = threadIdx.x & 63;
  int d = blockIdx.x * 4 + wave;
  if (d >= n) return;
  int begin = row_ptr[d];
  int end = row_ptr[d + 1];
  int hh = lane & 7;
  float ad = adst[d * 8 + hh];

  // Pass 1: per-head max, 8 edges x 8 heads in parallel.
  float m = -3.4e38f;
  for (int base = begin; base < end; base += 8) {
    int e = base + (lane >> 3);
    if (e < end) {
      int s = srcs[e];
      m = fmaxf(m, lrelu(asrc[s * 8 + hh] + ad));
    }
  }
  m = fmaxf(m, __shfl_xor(m, 8));
  m = fmaxf(m, __shfl_xor(m, 16));
  m = fmaxf(m, __shfl_xor(m, 32));
  // every lane now holds max for head lane&7

  const int myhead = lane >> 3;
  float denom = 0.f;
  float4 acc = make_float4(0.f, 0.f, 0.f, 0.f);
  int e = begin;
  for (; e + 4 <= end; e += 4) {
    int s0 = srcs[e + 0];
    int s1 = srcs[e + 1];
    int s2 = srcs[e + 2];
    int s3 = srcs[e + 3];
    float w0 = 0.f, w1 = 0.f, w2 = 0.f, w3 = 0.f;
    if (lane < 8) {
      w0 = __expf(lrelu(asrc[s0 * 8 + lane] + ad) - m);
      w1 = __expf(lrelu(asrc[s1 * 8 + lane] + ad) - m);
      w2 = __expf(lrelu(asrc[s2 * 8 + lane] + ad) - m);
      w3 = __expf(lrelu(asrc[s3 * 8 + lane] + ad) - m);
      denom += w0 + w1 + w2 + w3;
    }
    const float4 h0 = *(const float4*)&h[(size_t)s0 * 256 + lane * 4];
    const float4 h1 = *(const float4*)&h[(size_t)s1 * 256 + lane * 4];
    const float4 h2 = *(const float4*)&h[(size_t)s2 * 256 + lane * 4];
    const float4 h3 = *(const float4*)&h[(size_t)s3 * 256 + lane * 4];
    float wh0 = __shfl(w0, myhead);
    float wh1 = __shfl(w1, myhead);
    float wh2 = __shfl(w2, myhead);
    float wh3 = __shfl(w3, myhead);
    acc.x = fmaf(wh0, h0.x, acc.x); acc.y = fmaf(wh0, h0.y, acc.y);
    acc.z = fmaf(wh0, h0.z, acc.z); acc.w = fmaf(wh0, h0.w, acc.w);
    acc.x = fmaf(wh1, h1.x, acc.x); acc.y = fmaf(wh1, h1.y, acc.y);
    acc.z = fmaf(wh1, h1.z, acc.z); acc.w = fmaf(wh1, h1.w, acc.w);
    acc.x = fmaf(wh2, h2.x, acc.x); acc.y = fmaf(wh2, h2.y, acc.y);
    acc.z = fmaf(wh2, h2.z, acc.z); acc.w = fmaf(wh2, h2.w, acc.w);
    acc.x = fmaf(wh3, h3.x, acc.x); acc.y = fmaf(wh3, h3.y, acc.y);
    acc.z = fmaf(wh3, h3.z, acc.z); acc.w = fmaf(wh3, h3.w, acc.w);
  }
  for (; e < end; ++e) {
    int s = srcs[e];
    float w = 0.f;
    if (lane < 8) {
      w = __expf(lrelu(asrc[s * 8 + lane] + ad) - m);
      denom += w;
    }
    float wh = __shfl(w, myhead);
    const float4 hv = *(const float4*)&h[(size_t)s * 256 + lane * 4];
    acc.x = fmaf(wh, hv.x, acc.x);
    acc.y = fmaf(wh, hv.y, acc.y);
    acc.z = fmaf(wh, hv.z, acc.z);
    acc.w = fmaf(wh, hv.w, acc.w);
  }
  float dn = __shfl(denom, myhead) + 1e-16f;
  float inv = 1.f / dn;
  int f = lane * 4;
  float4 bv = *(const float4*)&bias[f];
  float4 r;
  r.x = lrelu(acc.x * inv + bv.x);
  r.y = lrelu(acc.y * inv + bv.y);
  r.z = lrelu(acc.z * inv + bv.z);
  r.w = lrelu(acc.w * inv + bv.w);
  *(float4*)&out[(size_t)d * 256 + f] = r;
}

// Layer 2: C=4, F=32. One wave per dst; 8 edges processed in parallel
// (lane = edge-group * 8 + head), float4 per (edge,head). No inner shuffles.
__global__ __launch_bounds__(256) void gat_agg_l2(const float* __restrict__ h,
                                                  const float* __restrict__ asrc,
                                                  const float* __restrict__ adst,
                                                  const int* __restrict__ row_ptr,
                                                  const int* __restrict__ srcs,
                                                  const float* __restrict__ bias,
                                                  float* __restrict__ out, int n) {
  int wave = threadIdx.x >> 6;
  int lane = threadIdx.x & 63;
  int d = blockIdx.x * 4 + wave;
  if (d >= n) return;
  int begin = row_ptr[d];
  int end = row_ptr[d + 1];
  int hh = lane & 7;
  int eg = lane >> 3;
  float ad = adst[d * 8 + hh];

  // Pass 1: per-head max.
  float m = -3.4e38f;
  for (int base = begin; base < end; base += 8) {
    int e = base + eg;
    if (e < end) {
      int s = srcs[e];
      m = fmaxf(m, lrelu(asrc[s * 8 + hh] + ad));
    }
  }
  m = fmaxf(m, __shfl_xor(m, 8));
  m = fmaxf(m, __shfl_xor(m, 16));
  m = fmaxf(m, __shfl_xor(m, 32));

  // Pass 2: weighted accumulate, 8 edges at once.
  float denom = 0.f;
  float4 acc = make_float4(0.f, 0.f, 0.f, 0.f);
  for (int base = begin; base < end; base += 8) {
    int e = base + eg;
    if (e < end) {
      int s = srcs[e];
      float w = __expf(lrelu(asrc[s * 8 + hh] + ad) - m);
      denom += w;
      const float4 hv = *(const float4*)&h[(size_t)s * 32 + hh * 4];
      acc.x = fmaf(w, hv.x, acc.x);
      acc.y = fmaf(w, hv.y, acc.y);
      acc.z = fmaf(w, hv.z, acc.z);
      acc.w = fmaf(w, hv.w, acc.w);
    }
  }
#pragma unroll
  for (int mask = 8; mask <= 32; mask <<= 1) {
    denom += __shfl_xor(denom, mask);
    acc.x += __shfl_xor(acc.x, mask);
    acc.y += __shfl_xor(acc.y, mask);
    acc.z += __shfl_xor(acc.z, mask);
    acc.w += __shfl_xor(acc.w, mask);
  }
  if (lane < 8) {
    float inv = 1.f / (denom + 1e-16f);
    int f = lane * 4;
    float4 bv = *(const float4*)&bias[f];
    float4 r;
    r.x = acc.x * inv + bv.x;
    r.y = acc.y * inv + bv.y;
    r.z = acc.z * inv + bv.z;
    r.w = acc.w * inv + bv.w;
    *(float4*)&out[(size_t)d * 32 + f] = r;
  }
}

// -------------------- launcher --------------------

extern "C" void kernel_launch(void* const* d_in, const int* in_sizes, int n_in,
                              void* d_out, int out_size, void* d_ws, size_t ws_size,
                              hipStream_t stream) {
  const float* x   = (const float*)d_in[0];
  const int*   ei  = (const int*)d_in[1];
  const float* W1  = (const float*)d_in[2];
  const float* as1 = (const float*)d_in[3];
  const float* ad1 = (const float*)d_in[4];
  const float* b1  = (const float*)d_in[5];
  const float* W2  = (const float*)d_in[6];
  const float* as2 = (const float*)d_in[7];
  const float* ad2 = (const float*)d_in[8];
  const float* b2  = (const float*)d_in[9];
  float* out = (float*)d_out;

  const int E = in_sizes[1] / 2;
  const int n = in_sizes[0] / 128;
  const int* srce = ei;
  const int* dste = ei + E;

  char* ws = (char*)d_ws;
  size_t off = 0;
  auto alloc = [&](size_t bytes) -> void* {
    void* p = ws + off;
    off = (off + bytes + 255) & ~(size_t)255;
    return p;
  };
  int* cnt      = (int*)alloc((size_t)n * 4);
  int* row_ptr  = (int*)alloc((size_t)(n + 1) * 4);
  int* cursor   = (int*)alloc((size_t)n * 4);
  int* bsum     = (int*)alloc(256 * 4);
  int* boff     = (int*)alloc(256 * 4);
  int* srcs     = (int*)alloc((size_t)(E + n) * 4);
  float* h1     = (float*)alloc((size_t)n * 256 * 4);
  float* a_s1   = (float*)alloc((size_t)n * 8 * 4);
  float* a_d1   = (float*)alloc((size_t)n * 8 * 4);
  float* x2     = (float*)alloc((size_t)n * 256 * 4);
  float* h2     = (float*)alloc((size_t)n * 32 * 4);
  float* a_s2   = (float*)alloc((size_t)n * 8 * 4);
  float* a_d2   = (float*)alloc((size_t)n * 8 * 4);

  const int tot = E + n;
  hipMemsetAsync(cnt, 0, (size_t)n * 4, stream);
  k_hist<<<(tot + 255) / 256, 256, 0, stream>>>(dste, E, n, cnt);
  const int nb = (n + 1023) / 1024;
  k_scan1<<<nb, 256, 0, stream>>>(cnt, n, bsum);
  k_scan2<<<1, 64, 0, stream>>>(bsum, nb, boff, row_ptr, n);
  k_scan3<<<nb, 256, 0, stream>>>(cnt, boff, n, row_ptr, cursor);
  k_scatter<<<(tot + 255) / 256, 256, 0, stream>>>(srce, dste, E, n, cursor, srcs);

  gemm1<<<(n + 63) / 64, 256, 0, stream>>>(x, W1, h1, n);
  calc_alpha<32><<<(n * 8 + 255) / 256, 256, 0, stream>>>(h1, as1, ad1, a_s1, a_d1, n);
  gat_agg_l1<<<(n + 3) / 4, 256, 0, stream>>>(h1, a_s1, a_d1, row_ptr, srcs, b1, x2, n);

  gemm2<<<(n + 63) / 64, 256, 0, stream>>>(x2, W2, h2, n);
  calc_alpha<4><<<(n * 8 + 255) / 256, 256, 0, stream>>>(h2, as2, ad2, a_s2, a_d2, n);
  gat_agg_l2<<<(n + 3) / 4, 256, 0, stream>>>(h2, a_s2, a_d2, row_ptr, srcs, b2, out, n);
}

// Round 3
// 404.244 us; speedup vs baseline: 1.4276x; 1.1355x over previous
//
#include <hip/hip_runtime.h>
#include <hip/hip_bf16.h>
#include <cstdint>
#include <cstddef>

// ---------------------------------------------------------------------------
// GAT 2-layer forward. N=50000, E=800000 (+N self loops), H=8 heads.
// Layer1: Fin=128 -> 8x32 (=256), lrelu(0.2). Layer2: 256 -> 8x4 (=32).
// R2: (a) h1 stored bf16 -> layer-1 gather bytes halved (threshold is
// bf16-floor x8, plenty of headroom); (b) attention logits computed in the
// GEMM epilogues from fp32 accumulators (calc_alpha kernels eliminated);
// (c) layer-1 aggregation unrolled x8 over edges.
// ---------------------------------------------------------------------------

__device__ __forceinline__ float lrelu(float a) { return a > 0.f ? a : 0.2f * a; }

__device__ __forceinline__ unsigned short f2bf(float f) {
  unsigned u = __float_as_uint(f);
  unsigned r = (u + 0x7fff + ((u >> 16) & 1)) >> 16;  // RNE
  return (unsigned short)r;
}
__device__ __forceinline__ float bf_lo(unsigned q) { return __uint_as_float(q << 16); }
__device__ __forceinline__ float bf_hi(unsigned q) { return __uint_as_float(q & 0xffff0000u); }

// -------------------- CSR build --------------------

__global__ __launch_bounds__(256) void k_hist(const int* __restrict__ dste, int E, int n,
                                              int* __restrict__ cnt) {
  int t = blockIdx.x * 256 + threadIdx.x;
  if (t >= E + n) return;
  int d = (t < E) ? dste[t] : (t - E);   // self-loop for node t-E
  atomicAdd(&cnt[d], 1);
}

__global__ __launch_bounds__(256) void k_scan1(const int* __restrict__ cnt, int n,
                                               int* __restrict__ bsum) {
  __shared__ int sb[256];
  int i0 = blockIdx.x * 1024 + threadIdx.x * 4;
  int s = 0;
#pragma unroll
  for (int j = 0; j < 4; j++) { int i = i0 + j; if (i < n) s += cnt[i]; }
  sb[threadIdx.x] = s;
  __syncthreads();
  for (int off = 128; off > 0; off >>= 1) {
    if (threadIdx.x < off) sb[threadIdx.x] += sb[threadIdx.x + off];
    __syncthreads();
  }
  if (threadIdx.x == 0) bsum[blockIdx.x] = sb[0];
}

__global__ void k_scan2(const int* __restrict__ bsum, int nb, int* __restrict__ boff,
                        int* __restrict__ row_ptr, int n) {
  if (threadIdx.x == 0 && blockIdx.x == 0) {
    int run = 0;
    for (int j = 0; j < nb; j++) { boff[j] = run; run += bsum[j]; }
    row_ptr[n] = run;
  }
}

__global__ __launch_bounds__(256) void k_scan3(const int* __restrict__ cnt,
                                               const int* __restrict__ boff, int n,
                                               int* __restrict__ row_ptr,
                                               int* __restrict__ cursor) {
  __shared__ int sb[256];
  int i0 = blockIdx.x * 1024 + threadIdx.x * 4;
  int c[4];
  int s = 0;
#pragma unroll
  for (int j = 0; j < 4; j++) { int i = i0 + j; c[j] = (i < n) ? cnt[i] : 0; s += c[j]; }
  sb[threadIdx.x] = s;
  __syncthreads();
  for (int off = 1; off < 256; off <<= 1) {
    int add = (threadIdx.x >= off) ? sb[threadIdx.x - off] : 0;
    __syncthreads();
    sb[threadIdx.x] += add;
    __syncthreads();
  }
  int excl = sb[threadIdx.x] - s + boff[blockIdx.x];
#pragma unroll
  for (int j = 0; j < 4; j++) {
    int i = i0 + j;
    if (i < n) { row_ptr[i] = excl; cursor[i] = excl; excl += c[j]; }
  }
}

__global__ __launch_bounds__(256) void k_scatter(const int* __restrict__ srce,
                                                 const int* __restrict__ dste, int E, int n,
                                                 int* __restrict__ cursor,
                                                 int* __restrict__ srcs) {
  int t = blockIdx.x * 256 + threadIdx.x;
  if (t >= E + n) return;
  int s, d;
  if (t < E) { s = srce[t]; d = dste[t]; } else { s = d = t - E; }
  int pos = atomicAdd(&cursor[d], 1);
  srcs[pos] = s;
}

// -------------------- GEMM1 + alpha epilogue --------------------

// X[M,128] @ W[128,256] -> h1 (bf16, [M,256]) + a_s1/a_d1 ([M,8], fp32).
// Block: 64 rows, 256 threads. Wave lanes == tc (cols), tr wave-uniform.
__global__ __launch_bounds__(256) void gemm1(const float* __restrict__ X,
                                             const float* __restrict__ W,
                                             const float* __restrict__ a_src,
                                             const float* __restrict__ a_dst,
                                             unsigned short* __restrict__ h1,
                                             float* __restrict__ a_s1,
                                             float* __restrict__ a_d1, int M) {
  __shared__ float lx[64 * 128];  // 32 KB
  int row0 = blockIdx.x * 64;
#pragma unroll
  for (int i = 0; i < 8; i++) {
    int j = threadIdx.x + 256 * i;   // float4 index, 2048 total
    int r = j >> 5;                  // row within tile
    float4 v = make_float4(0.f, 0.f, 0.f, 0.f);
    if (row0 + r < M) v = *(const float4*)&X[(size_t)row0 * 128 + (size_t)j * 4];
    *(float4*)&lx[j * 4] = v;
  }
  __syncthreads();
  int tc = threadIdx.x & 63;   // col group: cols 4*tc..4*tc+3  (== lane)
  int tr = threadIdx.x >> 6;   // row group: rows tr*16..tr*16+15
  const float* lrow = &lx[tr * 16 * 128];
  float4 acc[16];
#pragma unroll
  for (int i = 0; i < 16; i++) acc[i] = make_float4(0.f, 0.f, 0.f, 0.f);
  for (int k4 = 0; k4 < 128; k4 += 4) {
    float4 w0 = *(const float4*)&W[(k4 + 0) * 256 + tc * 4];
    float4 w1 = *(const float4*)&W[(k4 + 1) * 256 + tc * 4];
    float4 w2 = *(const float4*)&W[(k4 + 2) * 256 + tc * 4];
    float4 w3 = *(const float4*)&W[(k4 + 3) * 256 + tc * 4];
#pragma unroll
    for (int i = 0; i < 16; i++) {
      float4 xv = *(const float4*)&lrow[i * 128 + k4];  // wave-uniform b128 broadcast
      acc[i].x = fmaf(xv.x, w0.x, acc[i].x);
      acc[i].y = fmaf(xv.x, w0.y, acc[i].y);
      acc[i].z = fmaf(xv.x, w0.z, acc[i].z);
      acc[i].w = fmaf(xv.x, w0.w, acc[i].w);
      acc[i].x = fmaf(xv.y, w1.x, acc[i].x);
      acc[i].y = fmaf(xv.y, w1.y, acc[i].y);
      acc[i].z = fmaf(xv.y, w1.z, acc[i].z);
      acc[i].w = fmaf(xv.y, w1.w, acc[i].w);
      acc[i].x = fmaf(xv.z, w2.x, acc[i].x);
      acc[i].y = fmaf(xv.z, w2.y, acc[i].y);
      acc[i].z = fmaf(xv.z, w2.z, acc[i].z);
      acc[i].w = fmaf(xv.z, w2.w, acc[i].w);
      acc[i].x = fmaf(xv.w, w3.x, acc[i].x);
      acc[i].y = fmaf(xv.w, w3.y, acc[i].y);
      acc[i].z = fmaf(xv.w, w3.z, acc[i].z);
      acc[i].w = fmaf(xv.w, w3.w, acc[i].w);
    }
  }
  // epilogue: bf16 store + per-head alpha dots (fp32 accumulators).
  int hh = tc >> 3;            // head 0..7
  int c0 = (tc & 7) * 4;       // channel offset within head
  float4 asv = *(const float4*)&a_src[hh * 32 + c0];
  float4 adv = *(const float4*)&a_dst[hh * 32 + c0];
  bool writer = (tc & 7) == 0;
#pragma unroll
  for (int i = 0; i < 16; i++) {
    int r = row0 + tr * 16 + i;
    float ps = acc[i].x * asv.x;
    ps = fmaf(acc[i].y, asv.y, ps);
    ps = fmaf(acc[i].z, asv.z, ps);
    ps = fmaf(acc[i].w, asv.w, ps);
    float pd = acc[i].x * adv.x;
    pd = fmaf(acc[i].y, adv.y, pd);
    pd = fmaf(acc[i].z, adv.z, pd);
    pd = fmaf(acc[i].w, adv.w, pd);
    ps += __shfl_xor(ps, 1); ps += __shfl_xor(ps, 2); ps += __shfl_xor(ps, 4);
    pd += __shfl_xor(pd, 1); pd += __shfl_xor(pd, 2); pd += __shfl_xor(pd, 4);
    if (r < M) {
      uint2 p;
      p.x = (unsigned)f2bf(acc[i].x) | ((unsigned)f2bf(acc[i].y) << 16);
      p.y = (unsigned)f2bf(acc[i].z) | ((unsigned)f2bf(acc[i].w) << 16);
      *(uint2*)&h1[(size_t)r * 256 + tc * 4] = p;
      if (writer) { a_s1[r * 8 + hh] = ps; a_d1[r * 8 + hh] = pd; }
    }
  }
}

// -------------------- GEMM2 + alpha epilogue --------------------

// X[M,256] @ W[256,32] -> h2 ([M,32] fp32) + a_s2/a_d2. Each lane holds all 4
// channels of head tc for its rows -> alpha dots are in-lane, no shuffles.
__global__ __launch_bounds__(256) void gemm2(const float* __restrict__ X,
                                             const float* __restrict__ W,
                                             const float* __restrict__ a_src,
                                             const float* __restrict__ a_dst,
                                             float* __restrict__ h2,
                                             float* __restrict__ a_s2,
                                             float* __restrict__ a_d2, int M) {
  __shared__ float lx[64 * 132];  // padded stride 132
  int row0 = blockIdx.x * 64;
  int tc = threadIdx.x & 7;    // head; cols 4*tc..4*tc+3
  int tr = threadIdx.x >> 3;   // rows tr*2, tr*2+1
  float4 acc[2];
  acc[0] = make_float4(0.f, 0.f, 0.f, 0.f);
  acc[1] = make_float4(0.f, 0.f, 0.f, 0.f);
  for (int kk = 0; kk < 256; kk += 128) {
    __syncthreads();
#pragma unroll
    for (int i = 0; i < 8; i++) {
      int j = threadIdx.x + 256 * i;  // float4 index, 2048 total
      int r = j >> 5;
      int c = (j & 31) * 4;
      float4 v = make_float4(0.f, 0.f, 0.f, 0.f);
      if (row0 + r < M) v = *(const float4*)&X[(size_t)(row0 + r) * 256 + kk + c];
      *(float4*)&lx[r * 132 + c] = v;
    }
    __syncthreads();
    for (int k = 0; k < 128; k++) {
      float4 w4 = *(const float4*)&W[(kk + k) * 32 + tc * 4];
#pragma unroll
      for (int i = 0; i < 2; i++) {
        float xv = lx[(tr * 2 + i) * 132 + k];
        acc[i].x = fmaf(xv, w4.x, acc[i].x);
        acc[i].y = fmaf(xv, w4.y, acc[i].y);
        acc[i].z = fmaf(xv, w4.z, acc[i].z);
        acc[i].w = fmaf(xv, w4.w, acc[i].w);
      }
    }
  }
  float4 asv = *(const float4*)&a_src[tc * 4];
  float4 adv = *(const float4*)&a_dst[tc * 4];
#pragma unroll
  for (int i = 0; i < 2; i++) {
    int r = row0 + tr * 2 + i;
    if (r < M) {
      float ps = acc[i].x * asv.x;
      ps = fmaf(acc[i].y, asv.y, ps);
      ps = fmaf(acc[i].z, asv.z, ps);
      ps = fmaf(acc[i].w, asv.w, ps);
      float pd = acc[i].x * adv.x;
      pd = fmaf(acc[i].y, adv.y, pd);
      pd = fmaf(acc[i].z, adv.z, pd);
      pd = fmaf(acc[i].w, adv.w, pd);
      *(float4*)&h2[(size_t)r * 32 + tc * 4] = acc[i];
      a_s2[r * 8 + tc] = ps;
      a_d2[r * 8 + tc] = pd;
    }
  }
}

// -------------------- segment softmax + aggregation --------------------

// Layer 1: F=256 bf16. One wave per dst; lane owns 4 bf16 (8 B) at channel
// lane*4, head = lane>>3. Weighted-accumulate loop unrolled x8 for MLP.
__global__ __launch_bounds__(256) void gat_agg_l1(const unsigned short* __restrict__ h,
                                                  const float* __restrict__ asrc,
                                                  const float* __restrict__ adst,
                                                  const int* __restrict__ row_ptr,
                                                  const int* __restrict__ srcs,
                                                  const float* __restrict__ bias,
                                                  float* __restrict__ out, int n) {
  int wave = threadIdx.x >> 6;
  int lane = threadIdx.x & 63;
  int d = blockIdx.x * 4 + wave;
  if (d >= n) return;
  int begin = row_ptr[d];
  int end = row_ptr[d + 1];
  int hh = lane & 7;
  float ad = adst[d * 8 + hh];

  // Pass 1: per-head max, 8 edges x 8 heads in parallel.
  float m = -3.4e38f;
  for (int base = begin; base < end; base += 8) {
    int e = base + (lane >> 3);
    if (e < end) {
      int s = srcs[e];
      m = fmaxf(m, lrelu(asrc[s * 8 + hh] + ad));
    }
  }
  m = fmaxf(m, __shfl_xor(m, 8));
  m = fmaxf(m, __shfl_xor(m, 16));
  m = fmaxf(m, __shfl_xor(m, 32));
  // every lane now holds max for head lane&7

  const int myhead = lane >> 3;
  float denom = 0.f;
  float4 acc = make_float4(0.f, 0.f, 0.f, 0.f);
  int e = begin;
  for (; e + 8 <= end; e += 8) {
    int s0 = srcs[e + 0], s1 = srcs[e + 1], s2 = srcs[e + 2], s3 = srcs[e + 3];
    int s4 = srcs[e + 4], s5 = srcs[e + 5], s6 = srcs[e + 6], s7 = srcs[e + 7];
    float w0 = 0.f, w1 = 0.f, w2 = 0.f, w3 = 0.f;
    float w4 = 0.f, w5 = 0.f, w6 = 0.f, w7 = 0.f;
    if (lane < 8) {
      w0 = __expf(lrelu(asrc[s0 * 8 + lane] + ad) - m);
      w1 = __expf(lrelu(asrc[s1 * 8 + lane] + ad) - m);
      w2 = __expf(lrelu(asrc[s2 * 8 + lane] + ad) - m);
      w3 = __expf(lrelu(asrc[s3 * 8 + lane] + ad) - m);
      w4 = __expf(lrelu(asrc[s4 * 8 + lane] + ad) - m);
      w5 = __expf(lrelu(asrc[s5 * 8 + lane] + ad) - m);
      w6 = __expf(lrelu(asrc[s6 * 8 + lane] + ad) - m);
      w7 = __expf(lrelu(asrc[s7 * 8 + lane] + ad) - m);
      denom += (w0 + w1 + w2 + w3) + (w4 + w5 + w6 + w7);
    }
    uint2 q0 = *(const uint2*)&h[(size_t)s0 * 256 + lane * 4];
    uint2 q1 = *(const uint2*)&h[(size_t)s1 * 256 + lane * 4];
    uint2 q2 = *(const uint2*)&h[(size_t)s2 * 256 + lane * 4];
    uint2 q3 = *(const uint2*)&h[(size_t)s3 * 256 + lane * 4];
    uint2 q4 = *(const uint2*)&h[(size_t)s4 * 256 + lane * 4];
    uint2 q5 = *(const uint2*)&h[(size_t)s5 * 256 + lane * 4];
    uint2 q6 = *(const uint2*)&h[(size_t)s6 * 256 + lane * 4];
    uint2 q7 = *(const uint2*)&h[(size_t)s7 * 256 + lane * 4];
    float f0 = __shfl(w0, myhead), f1 = __shfl(w1, myhead);
    float f2 = __shfl(w2, myhead), f3 = __shfl(w3, myhead);
    float f4 = __shfl(w4, myhead), f5 = __shfl(w5, myhead);
    float f6 = __shfl(w6, myhead), f7 = __shfl(w7, myhead);
#define ACC4(ff, qq)                                      \
    acc.x = fmaf(ff, bf_lo(qq.x), acc.x);                 \
    acc.y = fmaf(ff, bf_hi(qq.x), acc.y);                 \
    acc.z = fmaf(ff, bf_lo(qq.y), acc.z);                 \
    acc.w = fmaf(ff, bf_hi(qq.y), acc.w);
    ACC4(f0, q0) ACC4(f1, q1) ACC4(f2, q2) ACC4(f3, q3)
    ACC4(f4, q4) ACC4(f5, q5) ACC4(f6, q6) ACC4(f7, q7)
  }
  for (; e < end; ++e) {
    int s = srcs[e];
    float w = 0.f;
    if (lane < 8) {
      w = __expf(lrelu(asrc[s * 8 + lane] + ad) - m);
      denom += w;
    }
    float wh = __shfl(w, myhead);
    uint2 q = *(const uint2*)&h[(size_t)s * 256 + lane * 4];
    ACC4(wh, q)
  }
#undef ACC4
  float dn = __shfl(denom, myhead) + 1e-16f;
  float inv = 1.f / dn;
  int f = lane * 4;
  float4 bv = *(const float4*)&bias[f];
  float4 r;
  r.x = lrelu(acc.x * inv + bv.x);
  r.y = lrelu(acc.y * inv + bv.y);
  r.z = lrelu(acc.z * inv + bv.z);
  r.w = lrelu(acc.w * inv + bv.w);
  *(float4*)&out[(size_t)d * 256 + f] = r;
}

// Layer 2: C=4, F=32. One wave per dst; 8 edges in parallel
// (lane = edge-group * 8 + head), float4 per (edge,head).
__global__ __launch_bounds__(256) void gat_agg_l2(const float* __restrict__ h,
                                                  const float* __restrict__ asrc,
                                                  const float* __restrict__ adst,
                                                  const int* __restrict__ row_ptr,
                                                  const int* __restrict__ srcs,
                                                  const float* __restrict__ bias,
                                                  float* __restrict__ out, int n) {
  int wave = threadIdx.x >> 6;
  int lane = threadIdx.x & 63;
  int d = blockIdx.x * 4 + wave;
  if (d >= n) return;
  int begin = row_ptr[d];
  int end = row_ptr[d + 1];
  int hh = lane & 7;
  int eg = lane >> 3;
  float ad = adst[d * 8 + hh];

  float m = -3.4e38f;
  for (int base = begin; base < end; base += 8) {
    int e = base + eg;
    if (e < end) {
      int s = srcs[e];
      m = fmaxf(m, lrelu(asrc[s * 8 + hh] + ad));
    }
  }
  m = fmaxf(m, __shfl_xor(m, 8));
  m = fmaxf(m, __shfl_xor(m, 16));
  m = fmaxf(m, __shfl_xor(m, 32));

  float denom = 0.f;
  float4 acc = make_float4(0.f, 0.f, 0.f, 0.f);
  for (int base = begin; base < end; base += 8) {
    int e = base + eg;
    if (e < end) {
      int s = srcs[e];
      float w = __expf(lrelu(asrc[s * 8 + hh] + ad) - m);
      denom += w;
      const float4 hv = *(const float4*)&h[(size_t)s * 32 + hh * 4];
      acc.x = fmaf(w, hv.x, acc.x);
      acc.y = fmaf(w, hv.y, acc.y);
      acc.z = fmaf(w, hv.z, acc.z);
      acc.w = fmaf(w, hv.w, acc.w);
    }
  }
#pragma unroll
  for (int mask = 8; mask <= 32; mask <<= 1) {
    denom += __shfl_xor(denom, mask);
    acc.x += __shfl_xor(acc.x, mask);
    acc.y += __shfl_xor(acc.y, mask);
    acc.z += __shfl_xor(acc.z, mask);
    acc.w += __shfl_xor(acc.w, mask);
  }
  if (lane < 8) {
    float inv = 1.f / (denom + 1e-16f);
    int f = lane * 4;
    float4 bv = *(const float4*)&bias[f];
    float4 r;
    r.x = acc.x * inv + bv.x;
    r.y = acc.y * inv + bv.y;
    r.z = acc.z * inv + bv.z;
    r.w = acc.w * inv + bv.w;
    *(float4*)&out[(size_t)d * 32 + f] = r;
  }
}

// -------------------- launcher --------------------

extern "C" void kernel_launch(void* const* d_in, const int* in_sizes, int n_in,
                              void* d_out, int out_size, void* d_ws, size_t ws_size,
                              hipStream_t stream) {
  const float* x   = (const float*)d_in[0];
  const int*   ei  = (const int*)d_in[1];
  const float* W1  = (const float*)d_in[2];
  const float* as1 = (const float*)d_in[3];
  const float* ad1 = (const float*)d_in[4];
  const float* b1  = (const float*)d_in[5];
  const float* W2  = (const float*)d_in[6];
  const float* as2 = (const float*)d_in[7];
  const float* ad2 = (const float*)d_in[8];
  const float* b2  = (const float*)d_in[9];
  float* out = (float*)d_out;

  const int E = in_sizes[1] / 2;
  const int n = in_sizes[0] / 128;
  const int* srce = ei;
  const int* dste = ei + E;

  char* ws = (char*)d_ws;
  size_t off = 0;
  auto alloc = [&](size_t bytes) -> void* {
    void* p = ws + off;
    off = (off + bytes + 255) & ~(size_t)255;
    return p;
  };
  int* cnt      = (int*)alloc((size_t)n * 4);
  int* row_ptr  = (int*)alloc((size_t)(n + 1) * 4);
  int* cursor   = (int*)alloc((size_t)n * 4);
  int* bsum     = (int*)alloc(256 * 4);
  int* boff     = (int*)alloc(256 * 4);
  int* srcs     = (int*)alloc((size_t)(E + n) * 4);
  unsigned short* h1 = (unsigned short*)alloc((size_t)n * 256 * 2);  // bf16
  float* a_s1   = (float*)alloc((size_t)n * 8 * 4);
  float* a_d1   = (float*)alloc((size_t)n * 8 * 4);
  float* x2     = (float*)alloc((size_t)n * 256 * 4);
  float* h2     = (float*)alloc((size_t)n * 32 * 4);
  float* a_s2   = (float*)alloc((size_t)n * 8 * 4);
  float* a_d2   = (float*)alloc((size_t)n * 8 * 4);

  const int tot = E + n;
  hipMemsetAsync(cnt, 0, (size_t)n * 4, stream);
  k_hist<<<(tot + 255) / 256, 256, 0, stream>>>(dste, E, n, cnt);
  const int nb = (n + 1023) / 1024;
  k_scan1<<<nb, 256, 0, stream>>>(cnt, n, bsum);
  k_scan2<<<1, 64, 0, stream>>>(bsum, nb, boff, row_ptr, n);
  k_scan3<<<nb, 256, 0, stream>>>(cnt, boff, n, row_ptr, cursor);
  k_scatter<<<(tot + 255) / 256, 256, 0, stream>>>(srce, dste, E, n, cursor, srcs);

  gemm1<<<(n + 63) / 64, 256, 0, stream>>>(x, W1, as1, ad1, h1, a_s1, a_d1, n);
  gat_agg_l1<<<(n + 3) / 4, 256, 0, stream>>>(h1, a_s1, a_d1, row_ptr, srcs, b1, x2, n);

  gemm2<<<(n + 63) / 64, 256, 0, stream>>>(x2, W2, as2, ad2, h2, a_s2, a_d2, n);
  gat_agg_l2<<<(n + 3) / 4, 256, 0, stream>>>(h2, a_s2, a_d2, row_ptr, srcs, b2, out, n);
}